// Round 7
// baseline (349.444 us; speedup 1.0000x reference)
//
#include <hip/hip_runtime.h>

#define D 128
#define LSTR 132  // padded LDS row stride (floats)

typedef __attribute__((ext_vector_type(8))) short short8;
typedef __attribute__((ext_vector_type(4))) float f32x4;

static __device__ __forceinline__ unsigned short f2bf(float f) {
    unsigned u = __float_as_uint(f);
    return (unsigned short)((u + 0x7fffu + ((u >> 16) & 1u)) >> 16);  // RNE
}
static __device__ __forceinline__ float b2f(unsigned short u) {
    return __uint_as_float(((unsigned)u) << 16);
}

// ---------------------------------------------------------------------------
// GraphSAGE (mean) x2 + head. bf16 features (fp32 accumulate), CSR gather
// aggregation (segmented), MFMA fused dual GEMM (mean pre-applied in LDS).
// CSR ranges are allocated per 64-row tile via atomicAdd (arbitrary global
// order, contiguous per tile) -- no multi-kernel scan.
// d_ws (ints): cnt[Npad] (gctr at cnt[Npad-1]) | cursor[Npad] | blk_range[4096]
//   | csr[Epad] | xb bf16[N*D] | hb bf16[N*D] | Bt1 bf16[128*256] | Bt2 ...
// ---------------------------------------------------------------------------

__global__ void prep_kernel(const float* __restrict__ x,
                            const float* __restrict__ W1l,
                            const float* __restrict__ W1r,
                            const float* __restrict__ W2l,
                            const float* __restrict__ W2r,
                            unsigned* __restrict__ xb2,
                            unsigned short* __restrict__ Bt1,
                            unsigned short* __restrict__ Bt2,
                            int* __restrict__ cnt, int NX2, int Ncnt) {
    const int i = blockIdx.x * blockDim.x + threadIdx.x;
    if (i < NX2) {
        const float2 v = *(const float2*)(x + 2 * (size_t)i);
        xb2[i] = (unsigned)f2bf(v.x) | ((unsigned)f2bf(v.y) << 16);
    } else if (i < NX2 + 2 * 32768) {
        const int j = i - NX2;
        const int which = j >> 15;  // 0 -> layer1, 1 -> layer2
        const int jj = j & 32767;
        const int n = jj >> 8;
        const int k = jj & 255;
        const float* Wl = which ? W2l : W1l;
        const float* Wr = which ? W2r : W1r;
        const float w = (k < 128) ? Wl[k * 128 + n] : Wr[(k - 128) * 128 + n];
        (which ? Bt2 : Bt1)[jj] = f2bf(w);
    } else if (i < NX2 + 2 * 32768 + Ncnt) {
        cnt[i - NX2 - 2 * 32768] = 0;  // includes gctr slot at Npad-1
    }
}

__global__ void hist_kernel(const int* __restrict__ dst, int E,
                            int* __restrict__ cnt) {
    int i = blockIdx.x * blockDim.x + threadIdx.x;
    if (i < E) atomicAdd(&cnt[dst[i]], 1);
}

// Per-64-row-tile CSR range allocation: 32-lane group prefix-sums its tile's
// counts, atomically grabs a contiguous base. Global tile order is arbitrary.
__global__ __launch_bounds__(256) void alloc_kernel(
    const int* __restrict__ cnt, int* __restrict__ cursor,
    int* __restrict__ blk_range, int* __restrict__ gctr, int nchunks) {
    const int c = blockIdx.x * 8 + (threadIdx.x >> 5);
    const int l = threadIdx.x & 31;
    if (c >= nchunks) return;
    const int r0 = c * 64;
    const int v0 = cnt[r0 + l];
    const int v1 = cnt[r0 + 32 + l];
    int s0 = v0, s1 = v1;
#pragma unroll
    for (int off = 1; off < 32; off <<= 1) {
        const int u0 = __shfl_up(s0, off, 32);
        const int u1 = __shfl_up(s1, off, 32);
        if (l >= off) { s0 += u0; s1 += u1; }
    }
    const int t0 = __shfl(s0, 31, 32);
    const int t1 = __shfl(s1, 31, 32);
    int base = 0;
    if (l == 0) base = atomicAdd(gctr, t0 + t1);
    base = __shfl(base, 0, 32);
    cursor[r0 + l] = base + s0 - v0;
    cursor[r0 + 32 + l] = base + t0 + s1 - v1;
    if (l == 0) {
        blk_range[2 * c] = base;
        blk_range[2 * c + 1] = base + t0 + t1;
    }
}

__global__ void fill_kernel(const int* __restrict__ src,
                            const int* __restrict__ dst, int E,
                            int* __restrict__ cursor,
                            unsigned* __restrict__ csr) {
    int e = blockIdx.x * blockDim.x + threadIdx.x;
    if (e < E) {
        int d = dst[e];
        int p = atomicAdd(&cursor[d], 1);
        csr[p] = (unsigned)src[e] | ((unsigned)d << 16);
    }
}

// Fused: segmented bf16 gather (fp32 acc) -> mean pre-scale in LDS -> single
// MFMA chain [agg|x](64x256) @ [Wl;Wr]^T. HEAD folds Linear(128,1).
template <bool HEAD>
__global__ __launch_bounds__(256) void sage_kernel(
    const unsigned short* __restrict__ xb, const unsigned* __restrict__ csr,
    const int* __restrict__ cnt, const int* __restrict__ blk_range,
    const unsigned short* __restrict__ Bt,  // [128 n][256 k] bf16
    const float* __restrict__ bl, const float* __restrict__ Wout,
    const float* __restrict__ bout, unsigned short* __restrict__ hb_out,
    float* __restrict__ out, int N) {
    __shared__ float aggL[64 * LSTR];
    __shared__ float invL[64];

    const int b = blockIdx.x;
    const int i0 = b * 64;
    const int t = threadIdx.x;
    const int g = t >> 5;
    const int l = t & 31;
    const int c4 = l << 2;

    for (int i = t; i < 64 * LSTR; i += 256) aggL[i] = 0.f;
    if (t < 64) invL[t] = 1.0f / fmaxf((float)cnt[i0 + t], 1.0f);
    __syncthreads();

    // ---- segmented edge-parallel aggregation ----
    const int rs0 = blk_range[2 * b];
    const int re0 = blk_range[2 * b + 1];
    const int nE = re0 - rs0;
    int e = rs0 + ((nE * g) >> 3);
    const int ee = rs0 + ((nE * (g + 1)) >> 3);

    float4 acc = make_float4(0.f, 0.f, 0.f, 0.f);
    int cur = (e < ee) ? (int)(csr[e] >> 16) - i0 : -1;

    auto load4 = [&](unsigned p) -> float4 {
        const ushort4 u =
            *(const ushort4*)(xb + (size_t)(p & 0xffffu) * D + c4);
        float4 v;
        v.x = b2f(u.x); v.y = b2f(u.y); v.z = b2f(u.z); v.w = b2f(u.w);
        return v;
    };
    auto step = [&](unsigned p, const float4& v) {
        const int r = (int)(p >> 16) - i0;
        if (r != cur) {
            float* q = aggL + cur * LSTR + c4;
            atomicAdd(q + 0, acc.x);
            atomicAdd(q + 1, acc.y);
            atomicAdd(q + 2, acc.z);
            atomicAdd(q + 3, acc.w);
            acc = make_float4(0.f, 0.f, 0.f, 0.f);
            cur = r;
        }
        acc.x += v.x; acc.y += v.y; acc.z += v.z; acc.w += v.w;
    };

    while (e + 8 <= ee) {
        const unsigned p0 = csr[e + 0], p1 = csr[e + 1];
        const unsigned p2 = csr[e + 2], p3 = csr[e + 3];
        const unsigned p4 = csr[e + 4], p5 = csr[e + 5];
        const unsigned p6 = csr[e + 6], p7 = csr[e + 7];
        const float4 v0 = load4(p0), v1 = load4(p1), v2 = load4(p2),
                     v3 = load4(p3), v4 = load4(p4), v5 = load4(p5),
                     v6 = load4(p6), v7 = load4(p7);
        step(p0, v0); step(p1, v1); step(p2, v2); step(p3, v3);
        step(p4, v4); step(p5, v5); step(p6, v6); step(p7, v7);
        e += 8;
    }
    while (e < ee) {
        const unsigned p = csr[e];
        step(p, load4(p));
        ++e;
    }
    if (cur >= 0) {
        float* q = aggL + cur * LSTR + c4;
        atomicAdd(q + 0, acc.x);
        atomicAdd(q + 1, acc.y);
        atomicAdd(q + 2, acc.z);
        atomicAdd(q + 3, acc.w);
    }
    __syncthreads();

    // ---- pre-scale agg by 1/deg (in place) ----
    for (int i4 = t; i4 < 64 * 32; i4 += 256) {
        const int row = i4 >> 5;
        const int cc = (i4 & 31) << 2;
        float4* p = (float4*)(aggL + row * LSTR + cc);
        float4 v = *p;
        const float inv = invL[row];
        v.x *= inv; v.y *= inv; v.z *= inv; v.w *= inv;
        *p = v;
    }
    __syncthreads();

    // ---- MFMA: wave handles 16 rows x 128 cols, K=256 ([agg|x]) ----
    const int wave = t >> 6;
    const int lane = t & 63;
    const int ln = lane & 15;
    const int quad = lane >> 4;
    const int mrow = wave * 16 + ln;
    const int gmr = i0 + mrow;

    f32x4 acc8[8] = {f32x4{0.f, 0.f, 0.f, 0.f}, f32x4{0.f, 0.f, 0.f, 0.f},
                     f32x4{0.f, 0.f, 0.f, 0.f}, f32x4{0.f, 0.f, 0.f, 0.f},
                     f32x4{0.f, 0.f, 0.f, 0.f}, f32x4{0.f, 0.f, 0.f, 0.f},
                     f32x4{0.f, 0.f, 0.f, 0.f}, f32x4{0.f, 0.f, 0.f, 0.f}};

#pragma unroll
    for (int s = 0; s < 4; ++s) {
        const int kb = s * 32 + quad * 8;
        const float* ap = aggL + mrow * LSTR + kb;
        const float4 fa = *(const float4*)ap;
        const float4 fb = *(const float4*)(ap + 4);
        const short8 aA = {(short)f2bf(fa.x), (short)f2bf(fa.y),
                           (short)f2bf(fa.z), (short)f2bf(fa.w),
                           (short)f2bf(fb.x), (short)f2bf(fb.y),
                           (short)f2bf(fb.z), (short)f2bf(fb.w)};
        short8 aX = {0, 0, 0, 0, 0, 0, 0, 0};
        if (gmr < N) aX = *(const short8*)(xb + (size_t)gmr * D + kb);
#pragma unroll
        for (int nt = 0; nt < 8; ++nt) {
            const int n = nt * 16 + ln;
            const short8 b1 = *(const short8*)(Bt + n * 256 + kb);
            const short8 b2 = *(const short8*)(Bt + n * 256 + 128 + kb);
            acc8[nt] =
                __builtin_amdgcn_mfma_f32_16x16x32_bf16(aA, b1, acc8[nt], 0, 0, 0);
            acc8[nt] =
                __builtin_amdgcn_mfma_f32_16x16x32_bf16(aX, b2, acc8[nt], 0, 0, 0);
        }
    }

    // ---- epilogue: C/D layout col=lane&15, row=quad*4+reg ----
    float biasv[8], woutv[8];
#pragma unroll
    for (int nt = 0; nt < 8; ++nt) {
        const int col = nt * 16 + ln;
        biasv[nt] = bl[col];
        if (HEAD) woutv[nt] = Wout[col];
    }

    if (!HEAD) {
#pragma unroll
        for (int r = 0; r < 4; ++r) {
            const int gr = i0 + wave * 16 + quad * 4 + r;
            if (gr < N) {
#pragma unroll
                for (int nt = 0; nt < 8; ++nt) {
                    const int col = nt * 16 + ln;
                    const float v = fmaxf(acc8[nt][r] + biasv[nt], 0.f);
                    hb_out[(size_t)gr * D + col] = f2bf(v);
                }
            }
        }
    } else {
        const float b0 = bout[0];
#pragma unroll
        for (int r = 0; r < 4; ++r) {
            const int gr = i0 + wave * 16 + quad * 4 + r;
            float p = 0.f;
#pragma unroll
            for (int nt = 0; nt < 8; ++nt) {
                const float v = fmaxf(acc8[nt][r] + biasv[nt], 0.f);
                p += v * woutv[nt];
            }
            p += __shfl_xor(p, 1);
            p += __shfl_xor(p, 2);
            p += __shfl_xor(p, 4);
            p += __shfl_xor(p, 8);
            if (ln == 0 && gr < N) out[gr] = p + b0;
        }
    }
}

extern "C" void kernel_launch(void* const* d_in, const int* in_sizes, int n_in,
                              void* d_out, int out_size, void* d_ws,
                              size_t ws_size, hipStream_t stream) {
    const float* x = (const float*)d_in[0];
    const int* ei = (const int*)d_in[1];
    const float* W1l = (const float*)d_in[2];
    const float* b1l = (const float*)d_in[3];
    const float* W1r = (const float*)d_in[4];
    const float* W2l = (const float*)d_in[5];
    const float* b2l = (const float*)d_in[6];
    const float* W2r = (const float*)d_in[7];
    const float* Wout = (const float*)d_in[8];
    const float* bout = (const float*)d_in[9];

    const int N = in_sizes[0] / D;
    const int E = in_sizes[1] / 2;
    const int* src = ei;
    const int* dst = ei + E;

    const size_t Npad = (size_t)((N + 66 + 255) & ~255);
    const size_t Epad = (size_t)((E + 255) & ~255);
    int* cnt = (int*)d_ws;
    int* gctr = cnt + Npad - 1;
    int* cursor = cnt + Npad;
    int* blk_range = cursor + Npad;
    unsigned* csr = (unsigned*)(blk_range + 4096);
    unsigned short* xb = (unsigned short*)(csr + Epad);
    unsigned short* hb = xb + (size_t)N * D;
    unsigned short* Bt1 = hb + (size_t)N * D;
    unsigned short* Bt2 = Bt1 + 128 * 256;
    float* out = (float*)d_out;

    const int nchunks = (N + 63) / 64;
    const int NX2 = N * D / 2;
    const int prep_total = NX2 + 2 * 32768 + (int)Npad;

    prep_kernel<<<(prep_total + 255) / 256, 256, 0, stream>>>(
        x, W1l, W1r, W2l, W2r, (unsigned*)xb, Bt1, Bt2, cnt, NX2, (int)Npad);
    hist_kernel<<<(E + 255) / 256, 256, 0, stream>>>(dst, E, cnt);
    alloc_kernel<<<(nchunks + 7) / 8, 256, 0, stream>>>(cnt, cursor, blk_range,
                                                        gctr, nchunks);
    fill_kernel<<<(E + 255) / 256, 256, 0, stream>>>(src, dst, E, cursor, csr);

    sage_kernel<false><<<nchunks, 256, 0, stream>>>(
        xb, csr, cnt, blk_range, Bt1, b1l, nullptr, nullptr, hb, nullptr, N);
    sage_kernel<true><<<nchunks, 256, 0, stream>>>(
        hb, csr, cnt, blk_range, Bt2, b2l, Wout, bout, nullptr, out, N);
}

// Round 8
// 313.937 us; speedup vs baseline: 1.1131x; 1.1131x over previous
//
#include <hip/hip_runtime.h>

#define D 128
#define LSTR 132  // padded LDS row stride (floats)

typedef __attribute__((ext_vector_type(8))) short short8;
typedef __attribute__((ext_vector_type(4))) float f32x4;

static __device__ __forceinline__ unsigned short f2bf(float f) {
    unsigned u = __float_as_uint(f);
    return (unsigned short)((u + 0x7fffu + ((u >> 16) & 1u)) >> 16);  // RNE
}
static __device__ __forceinline__ float b2f(unsigned short u) {
    return __uint_as_float(((unsigned)u) << 16);
}

// ---------------------------------------------------------------------------
// GraphSAGE (mean) x2 + head. bf16 features (fp32 accumulate), CSR gather
// aggregation (segmented, 32-row tiles), MFMA fused dual GEMM; mean applied
// during A-fragment construction. CSR ranges allocated per 32-row tile via
// atomicAdd (contiguous per tile, arbitrary global order).
// d_ws (ints): cnt[Npad] (gctr at cnt[Npad-1]) | cursor[Npad] | blk_range[4096]
//   | csr[Epad] | xb bf16[N*D] | hb bf16[N*D] | Bt1 bf16[128*256] | Bt2 ...
// ---------------------------------------------------------------------------

__global__ void prep_kernel(const float* __restrict__ x,
                            const float* __restrict__ W1l,
                            const float* __restrict__ W1r,
                            const float* __restrict__ W2l,
                            const float* __restrict__ W2r,
                            unsigned* __restrict__ xb2,
                            unsigned short* __restrict__ Bt1,
                            unsigned short* __restrict__ Bt2,
                            int* __restrict__ cnt, int NX2, int Ncnt) {
    const int i = blockIdx.x * blockDim.x + threadIdx.x;
    if (i < NX2) {
        const float2 v = *(const float2*)(x + 2 * (size_t)i);
        xb2[i] = (unsigned)f2bf(v.x) | ((unsigned)f2bf(v.y) << 16);
    } else if (i < NX2 + 2 * 32768) {
        const int j = i - NX2;
        const int which = j >> 15;  // 0 -> layer1, 1 -> layer2
        const int jj = j & 32767;
        const int n = jj >> 8;
        const int k = jj & 255;
        const float* Wl = which ? W2l : W1l;
        const float* Wr = which ? W2r : W1r;
        const float w = (k < 128) ? Wl[k * 128 + n] : Wr[(k - 128) * 128 + n];
        (which ? Bt2 : Bt1)[jj] = f2bf(w);
    } else if (i < NX2 + 2 * 32768 + Ncnt) {
        cnt[i - NX2 - 2 * 32768] = 0;  // includes gctr slot at Npad-1
    }
}

__global__ void hist_kernel(const int* __restrict__ dst, int E,
                            int* __restrict__ cnt) {
    int i = blockIdx.x * blockDim.x + threadIdx.x;
    if (i < E) atomicAdd(&cnt[dst[i]], 1);
}

// Per-32-row-tile CSR range allocation: each 32-lane group prefix-sums its
// tile's counts and atomically grabs a contiguous base.
__global__ __launch_bounds__(256) void alloc_kernel(
    const int* __restrict__ cnt, int* __restrict__ cursor,
    int* __restrict__ blk_range, int* __restrict__ gctr, int nchunks) {
    const int c = blockIdx.x * 8 + (threadIdx.x >> 5);
    const int l = threadIdx.x & 31;
    if (c >= nchunks) return;
    const int r0 = c * 32;
    const int v = cnt[r0 + l];
    int s = v;
#pragma unroll
    for (int off = 1; off < 32; off <<= 1) {
        const int u = __shfl_up(s, off, 32);
        if (l >= off) s += u;
    }
    const int tot = __shfl(s, 31, 32);
    int base = 0;
    if (l == 0) base = atomicAdd(gctr, tot);
    base = __shfl(base, 0, 32);
    cursor[r0 + l] = base + s - v;
    if (l == 0) {
        blk_range[2 * c] = base;
        blk_range[2 * c + 1] = base + tot;
    }
}

__global__ void fill_kernel(const int* __restrict__ src,
                            const int* __restrict__ dst, int E,
                            int* __restrict__ cursor,
                            unsigned* __restrict__ csr) {
    int e = blockIdx.x * blockDim.x + threadIdx.x;
    if (e < E) {
        int d = dst[e];
        int p = atomicAdd(&cursor[d], 1);
        csr[p] = (unsigned)src[e] | ((unsigned)d << 16);
    }
}

// Fused: segmented bf16 gather (fp32 acc into LDS) -> MFMA dual GEMM with
// mean applied at A-frag build. HEAD folds the Linear(128,1).
template <bool HEAD>
__global__ __launch_bounds__(256) void sage_kernel(
    const unsigned short* __restrict__ xb, const unsigned* __restrict__ csr,
    const int* __restrict__ cnt, const int* __restrict__ blk_range,
    const unsigned short* __restrict__ Bt,  // [128 n][256 k] bf16
    const float* __restrict__ bl, const float* __restrict__ Wout,
    const float* __restrict__ bout, unsigned short* __restrict__ hb_out,
    float* __restrict__ out, int N) {
    __shared__ float aggL[32 * LSTR];
    __shared__ float invL[32];
    __shared__ float redH[32 * 2];

    const int b = blockIdx.x;
    const int i0 = b * 32;
    const int t = threadIdx.x;
    const int g = t >> 5;
    const int l = t & 31;
    const int c4 = l << 2;

    for (int i = t; i < 32 * LSTR; i += 256) aggL[i] = 0.f;
    if (t < 32) invL[t] = 1.0f / fmaxf((float)cnt[i0 + t], 1.0f);
    __syncthreads();

    // ---- segmented edge-parallel aggregation ----
    const int rs0 = blk_range[2 * b];
    const int re0 = blk_range[2 * b + 1];
    const int nE = re0 - rs0;
    int e = rs0 + ((nE * g) >> 3);
    const int ee = rs0 + ((nE * (g + 1)) >> 3);

    float4 acc = make_float4(0.f, 0.f, 0.f, 0.f);
    int cur = (e < ee) ? (int)(csr[e] >> 16) - i0 : -1;

    auto load4 = [&](unsigned p) -> float4 {
        const ushort4 u =
            *(const ushort4*)(xb + (size_t)(p & 0xffffu) * D + c4);
        float4 v;
        v.x = b2f(u.x); v.y = b2f(u.y); v.z = b2f(u.z); v.w = b2f(u.w);
        return v;
    };
    auto step = [&](unsigned p, const float4& v) {
        const int r = (int)(p >> 16) - i0;
        if (r != cur) {
            float* q = aggL + cur * LSTR + c4;
            atomicAdd(q + 0, acc.x);
            atomicAdd(q + 1, acc.y);
            atomicAdd(q + 2, acc.z);
            atomicAdd(q + 3, acc.w);
            acc = make_float4(0.f, 0.f, 0.f, 0.f);
            cur = r;
        }
        acc.x += v.x; acc.y += v.y; acc.z += v.z; acc.w += v.w;
    };

    while (e + 8 <= ee) {
        const unsigned p0 = csr[e + 0], p1 = csr[e + 1];
        const unsigned p2 = csr[e + 2], p3 = csr[e + 3];
        const unsigned p4 = csr[e + 4], p5 = csr[e + 5];
        const unsigned p6 = csr[e + 6], p7 = csr[e + 7];
        const float4 v0 = load4(p0), v1 = load4(p1), v2 = load4(p2),
                     v3 = load4(p3), v4 = load4(p4), v5 = load4(p5),
                     v6 = load4(p6), v7 = load4(p7);
        step(p0, v0); step(p1, v1); step(p2, v2); step(p3, v3);
        step(p4, v4); step(p5, v5); step(p6, v6); step(p7, v7);
        e += 8;
    }
    while (e < ee) {
        const unsigned p = csr[e];
        step(p, load4(p));
        ++e;
    }
    if (cur >= 0) {
        float* q = aggL + cur * LSTR + c4;
        atomicAdd(q + 0, acc.x);
        atomicAdd(q + 1, acc.y);
        atomicAdd(q + 2, acc.z);
        atomicAdd(q + 3, acc.w);
    }
    __syncthreads();

    // ---- MFMA dual GEMM: [agg*inv | x](32x256) @ Bt^T(256x128) ----
    const int wave = t >> 6;
    const int lane = t & 63;
    const int ln = lane & 15;
    const int quad = lane >> 4;
    const int mtile = wave & 1;       // rows mtile*16..+15
    const int nt0 = (wave >> 1) * 4;  // 4 n-tiles per wave
    const int mrow = mtile * 16 + ln;
    const int gmr = i0 + mrow;
    const float inv = invL[mrow];

    f32x4 acc4[4] = {f32x4{0.f, 0.f, 0.f, 0.f}, f32x4{0.f, 0.f, 0.f, 0.f},
                     f32x4{0.f, 0.f, 0.f, 0.f}, f32x4{0.f, 0.f, 0.f, 0.f}};

#pragma unroll
    for (int s = 0; s < 4; ++s) {
        const int kb = s * 32 + quad * 8;
        const float* ap = aggL + mrow * LSTR + kb;
        const float4 fa = *(const float4*)ap;
        const float4 fb = *(const float4*)(ap + 4);
        const short8 aA = {(short)f2bf(fa.x * inv), (short)f2bf(fa.y * inv),
                           (short)f2bf(fa.z * inv), (short)f2bf(fa.w * inv),
                           (short)f2bf(fb.x * inv), (short)f2bf(fb.y * inv),
                           (short)f2bf(fb.z * inv), (short)f2bf(fb.w * inv)};
        short8 aX = {0, 0, 0, 0, 0, 0, 0, 0};
        if (gmr < N) aX = *(const short8*)(xb + (size_t)gmr * D + kb);
#pragma unroll
        for (int nt = 0; nt < 4; ++nt) {
            const int n = (nt0 + nt) * 16 + ln;
            const short8 b1 = *(const short8*)(Bt + n * 256 + kb);
            const short8 b2 = *(const short8*)(Bt + n * 256 + 128 + kb);
            acc4[nt] = __builtin_amdgcn_mfma_f32_16x16x32_bf16(aA, b1, acc4[nt],
                                                               0, 0, 0);
            acc4[nt] = __builtin_amdgcn_mfma_f32_16x16x32_bf16(aX, b2, acc4[nt],
                                                               0, 0, 0);
        }
    }

    // ---- epilogue: C/D layout col=lane&15, row=quad*4+reg ----
    float biasv[4], woutv[4];
#pragma unroll
    for (int nt = 0; nt < 4; ++nt) {
        const int col = (nt0 + nt) * 16 + ln;
        biasv[nt] = bl[col];
        if (HEAD) woutv[nt] = Wout[col];
    }

    if (!HEAD) {
#pragma unroll
        for (int r = 0; r < 4; ++r) {
            const int gr = i0 + mtile * 16 + quad * 4 + r;
            if (gr < N) {
#pragma unroll
                for (int nt = 0; nt < 4; ++nt) {
                    const int col = (nt0 + nt) * 16 + ln;
                    const float v = fmaxf(acc4[nt][r] + biasv[nt], 0.f);
                    hb_out[(size_t)gr * D + col] = f2bf(v);
                }
            }
        }
    } else {
        const float b0 = bout[0];
#pragma unroll
        for (int r = 0; r < 4; ++r) {
            const int row = mtile * 16 + quad * 4 + r;
            float p = 0.f;
#pragma unroll
            for (int nt = 0; nt < 4; ++nt) {
                const float v = fmaxf(acc4[nt][r] + biasv[nt], 0.f);
                p += v * woutv[nt];
            }
            p += __shfl_xor(p, 1);
            p += __shfl_xor(p, 2);
            p += __shfl_xor(p, 4);
            p += __shfl_xor(p, 8);
            if (ln == 0) redH[row * 2 + (wave >> 1)] = p;
        }
        __syncthreads();
        if (t < 32) {
            const int gr = i0 + t;
            if (gr < N) out[gr] = redH[t * 2] + redH[t * 2 + 1] + b0;
        }
    }
}

extern "C" void kernel_launch(void* const* d_in, const int* in_sizes, int n_in,
                              void* d_out, int out_size, void* d_ws,
                              size_t ws_size, hipStream_t stream) {
    const float* x = (const float*)d_in[0];
    const int* ei = (const int*)d_in[1];
    const float* W1l = (const float*)d_in[2];
    const float* b1l = (const float*)d_in[3];
    const float* W1r = (const float*)d_in[4];
    const float* W2l = (const float*)d_in[5];
    const float* b2l = (const float*)d_in[6];
    const float* W2r = (const float*)d_in[7];
    const float* Wout = (const float*)d_in[8];
    const float* bout = (const float*)d_in[9];

    const int N = in_sizes[0] / D;
    const int E = in_sizes[1] / 2;
    const int* src = ei;
    const int* dst = ei + E;

    const size_t Npad = (size_t)((N + 66 + 255) & ~255);
    const size_t Epad = (size_t)((E + 255) & ~255);
    int* cnt = (int*)d_ws;
    int* gctr = cnt + Npad - 1;
    int* cursor = cnt + Npad;
    int* blk_range = cursor + Npad;
    unsigned* csr = (unsigned*)(blk_range + 4096);
    unsigned short* xb = (unsigned short*)(csr + Epad);
    unsigned short* hb = xb + (size_t)N * D;
    unsigned short* Bt1 = hb + (size_t)N * D;
    unsigned short* Bt2 = Bt1 + 128 * 256;
    float* out = (float*)d_out;

    const int nchunks = (N + 31) / 32;
    const int NX2 = N * D / 2;
    const int prep_total = NX2 + 2 * 32768 + (int)Npad;

    prep_kernel<<<(prep_total + 255) / 256, 256, 0, stream>>>(
        x, W1l, W1r, W2l, W2r, (unsigned*)xb, Bt1, Bt2, cnt, NX2, (int)Npad);
    hist_kernel<<<(E + 255) / 256, 256, 0, stream>>>(dst, E, cnt);
    alloc_kernel<<<(nchunks + 7) / 8, 256, 0, stream>>>(cnt, cursor, blk_range,
                                                        gctr, nchunks);
    fill_kernel<<<(E + 255) / 256, 256, 0, stream>>>(src, dst, E, cursor, csr);

    sage_kernel<false><<<nchunks, 256, 0, stream>>>(
        xb, csr, cnt, blk_range, Bt1, b1l, nullptr, nullptr, hb, nullptr, N);
    sage_kernel<true><<<nchunks, 256, 0, stream>>>(
        hb, csr, cnt, blk_range, Bt2, b2l, Wout, bout, nullptr, out, N);
}